// Round 6
// baseline (319.520 us; speedup 1.0000x reference)
//
#include <hip/hip_runtime.h>
#include <hip/hip_bf16.h>

#define B_  8
#define N_  2048
#define KD_ 256
#define AD_ 128
#define VD_ 256
#define PAD80 80   // padded LDS stride (shorts): 160 B, multiple of 16 B

using s16x8 = __attribute__((ext_vector_type(8))) short;
using f16x8 = __attribute__((ext_vector_type(8))) _Float16;
using f32x4 = __attribute__((ext_vector_type(4))) float;

__device__ __forceinline__ f32x4 mfma16(s16x8 a, s16x8 b, f32x4 c) {
  return __builtin_amdgcn_mfma_f32_16x16x32_f16(
      __builtin_bit_cast(f16x8, a), __builtin_bit_cast(f16x8, b), c, 0, 0, 0);
}

// float -> fp16 bits
__device__ __forceinline__ short f2h(float f) {
  _Float16 h = (_Float16)f;
  return *reinterpret_cast<short*>(&h);
}

// convert 8 consecutive fp32 -> fp16x8 (as shorts)
__device__ __forceinline__ s16x8 cvt8(const float* __restrict__ p) {
  union { s16x8 v; short s[8]; } u;
  #pragma unroll
  for (int j = 0; j < 8; j++) u.s[j] = f2h(p[j]);
  return u.v;
}

// ---------------- W transpose+convert: WT[n][k] = f16(W[k][n]), W fp32 [256][128]
__global__ void transW_k(const float* __restrict__ W1, const float* __restrict__ W2,
                         short* __restrict__ WT1, short* __restrict__ WT2) {
  const float* W = blockIdx.x ? W2 : W1;
  short* WT      = blockIdx.x ? WT2 : WT1;
  for (int i = threadIdx.x; i < KD_ * AD_; i += blockDim.x) {
    int k = i >> 7, n = i & 127;
    WT[n * KD_ + k] = f2h(W[i]);
  }
}

// ---------------- projection: Y[m][n] = f16(X[m][:]@W[:][n] + bias[n]) ------
// X fp32 [16384][256], WT f16 [128][256] (pre-transposed), Y f16 [16384][128]
__global__ __launch_bounds__(256, 2) void proj_k(
    const float* __restrict__ X, const short* __restrict__ WT,
    const float* __restrict__ bias, short* __restrict__ Y) {
  __shared__ __align__(16) short sA[64 * 264];   // 264*2 = 528 B, mult of 16
  const int t    = threadIdx.x;
  const int m0   = blockIdx.x * 64;
  const int lane = t & 63, wave = t >> 6, quad = lane >> 4, l16 = lane & 15;
  #pragma unroll
  for (int i = 0; i < 8; i++) {
    int chunk = i * 256 + t;               // 2048 chunks = 64 rows * 32
    int row = chunk >> 5, c8 = chunk & 31;
    *(s16x8*)&sA[row * 264 + c8 * 8] =
        cvt8(&X[((size_t)(m0 + row)) * KD_ + c8 * 8]);
  }
  __syncthreads();
  f32x4 acc[8];
  #pragma unroll
  for (int nt = 0; nt < 8; nt++) acc[nt] = (f32x4){0.f, 0.f, 0.f, 0.f};
  #pragma unroll
  for (int ks = 0; ks < 8; ks++) {
    s16x8 a = *(const s16x8*)&sA[(wave * 16 + l16) * 264 + ks * 32 + quad * 8];
    #pragma unroll
    for (int nt = 0; nt < 8; nt++) {
      s16x8 bf = *(const s16x8*)&WT[(nt * 16 + l16) * KD_ + ks * 32 + quad * 8];
      acc[nt] = mfma16(a, bf, acc[nt]);
    }
  }
  #pragma unroll
  for (int nt = 0; nt < 8; nt++) {
    float bv = bias[nt * 16 + l16];
    #pragma unroll
    for (int r = 0; r < 4; r++) {
      int row = m0 + wave * 16 + quad * 4 + r;
      Y[(size_t)row * AD_ + nt * 16 + l16] = f2h(acc[nt][r] + bv);
    }
  }
}

// ---------------- flash attention (one pass per blockIdx.z) -----------------
// Q,K: [B][N][128] f16 (projected); V: [B][N][256] fp32 (original layout)
// O = softmax(Q K^T, -1) @ V, written fp32 [B][N][256]
__global__ __launch_bounds__(256, 2) void attn_k(
    const short* __restrict__ q1p, const short* __restrict__ q2p,
    const float* __restrict__ v1, const float* __restrict__ v2,
    float* __restrict__ out) {
  __shared__ __align__(16) short sK[64 * 136];        // 136*2 = 272 B, mult 16
  __shared__ __align__(16) short sVT[256 * PAD80];    // V^T tile: [v][key]
  __shared__ __align__(16) short sP[4][16 * PAD80];   // per-wave P round-trip

  const int t    = threadIdx.x;
  const int lane = t & 63, wave = t >> 6, quad = lane >> 4, l16 = lane & 15;
  const int q0   = blockIdx.x * 64;
  const int b    = blockIdx.y;
  const int pass = blockIdx.z;
  const short* Q = pass ? q2p : q1p;
  const short* K = pass ? q1p : q2p;
  const float* V = pass ? v1  : v2;
  float* O = out + (size_t)pass * ((size_t)B_ * N_ * VD_);

  // stage Q tile (64x128) into sK, pull q-fragments to registers
  #pragma unroll
  for (int i = 0; i < 4; i++) {
    int chunk = i * 256 + t;               // 1024 chunks = 64 rows * 16
    int row = chunk >> 4, c8 = chunk & 15;
    *(s16x8*)&sK[row * 136 + c8 * 8] =
        *(const s16x8*)&Q[((size_t)(b * N_ + q0 + row)) * AD_ + c8 * 8];
  }
  __syncthreads();
  s16x8 qf[4];
  #pragma unroll
  for (int ks = 0; ks < 4; ks++)
    qf[ks] = *(const s16x8*)&sK[(wave * 16 + l16) * 136 + ks * 32 + quad * 8];
  __syncthreads();

  float m_i[4], l_i[4];
  #pragma unroll
  for (int r = 0; r < 4; r++) { m_i[r] = -1e30f; l_i[r] = 0.f; }
  f32x4 acc[16];
  #pragma unroll
  for (int c = 0; c < 16; c++) acc[c] = (f32x4){0.f, 0.f, 0.f, 0.f};

  for (int kt = 0; kt < N_ / 64; kt++) {
    const int k0 = kt * 64;
    // stage K tile (64 keys x 128) from projected f16
    #pragma unroll
    for (int i = 0; i < 4; i++) {
      int chunk = i * 256 + t;
      int row = chunk >> 4, c8 = chunk & 15;
      *(s16x8*)&sK[row * 136 + c8 * 8] =
          *(const s16x8*)&K[((size_t)(b * N_ + k0 + row)) * AD_ + c8 * 8];
    }
    // stage V tile (64 keys x 256 v) fp32 -> transposed f16 sVT[v][key]
    {
      const float* src = &V[((size_t)(b * N_ + k0 + lane)) * VD_ + wave * 64];
      #pragma unroll
      for (int j = 0; j < 16; j++) {
        f32x4 f = *(const f32x4*)&src[4 * j];
        #pragma unroll
        for (int jj = 0; jj < 4; jj++)
          sVT[(wave * 64 + 4 * j + jj) * PAD80 + lane] = f2h(f[jj]);
      }
    }
    __syncthreads();

    // S = Q K^T : per wave 16x64 (4 col-tiles), K-dim 128 = 4 mfma steps
    f32x4 s[4];
    #pragma unroll
    for (int nt = 0; nt < 4; nt++) s[nt] = (f32x4){0.f, 0.f, 0.f, 0.f};
    #pragma unroll
    for (int ks = 0; ks < 4; ks++) {
      #pragma unroll
      for (int nt = 0; nt < 4; nt++) {
        s16x8 bfrag = *(const s16x8*)&sK[(nt * 16 + l16) * 136 + ks * 32 + quad * 8];
        s[nt] = mfma16(qf[ks], bfrag, s[nt]);
      }
    }

    // online softmax: rows quad*4+r, cols spread over 16 lanes + 4 tiles
    float alpha[4];
    #pragma unroll
    for (int r = 0; r < 4; r++) {
      float m = fmaxf(fmaxf(s[0][r], s[1][r]), fmaxf(s[2][r], s[3][r]));
      #pragma unroll
      for (int off = 1; off < 16; off <<= 1) m = fmaxf(m, __shfl_xor(m, off));
      float mn = fmaxf(m_i[r], m);
      alpha[r] = __expf(m_i[r] - mn);
      m_i[r]   = mn;
      float sum = 0.f;
      #pragma unroll
      for (int nt = 0; nt < 4; nt++) {
        float p = __expf(s[nt][r] - mn);
        s[nt][r] = p;
        sum += p;
      }
      #pragma unroll
      for (int off = 1; off < 16; off <<= 1) sum += __shfl_xor(sum, off);
      l_i[r] = l_i[r] * alpha[r] + sum;
    }
    #pragma unroll
    for (int c = 0; c < 16; c++) {
      #pragma unroll
      for (int r = 0; r < 4; r++) acc[c][r] *= alpha[r];
    }
    // P: D-layout regs -> per-wave LDS (row-major 16x64, stride PAD80)
    #pragma unroll
    for (int nt = 0; nt < 4; nt++) {
      #pragma unroll
      for (int r = 0; r < 4; r++)
        sP[wave][(quad * 4 + r) * PAD80 + nt * 16 + l16] = f2h(s[nt][r]);
    }
    __syncthreads();

    // O += P @ V : A = P (A-layout), B = V^T tile, 16 v-col-tiles x 2 k-steps
    #pragma unroll
    for (int ks2 = 0; ks2 < 2; ks2++) {
      s16x8 af = *(const s16x8*)&sP[wave][l16 * PAD80 + ks2 * 32 + quad * 8];
      #pragma unroll
      for (int nt2 = 0; nt2 < 16; nt2++) {
        s16x8 bfrag = *(const s16x8*)&sVT[(nt2 * 16 + l16) * PAD80 + ks2 * 32 + quad * 8];
        acc[nt2] = mfma16(af, bfrag, acc[nt2]);
      }
    }
    __syncthreads();
  }

  // epilogue: normalize and store fp32
  #pragma unroll
  for (int r = 0; r < 4; r++) {
    float inv = 1.f / l_i[r];
    int row = q0 + wave * 16 + quad * 4 + r;
    #pragma unroll
    for (int nt2 = 0; nt2 < 16; nt2++) {
      O[((size_t)(b * N_ + row)) * VD_ + nt2 * 16 + l16] = acc[nt2][r] * inv;
    }
  }
}

extern "C" void kernel_launch(void* const* d_in, const int* in_sizes, int n_in,
                              void* d_out, int out_size, void* d_ws, size_t ws_size,
                              hipStream_t stream) {
  const float* k1 = (const float*)d_in[0];
  const float* k2 = (const float*)d_in[1];
  const float* v1 = (const float*)d_in[2];
  const float* v2 = (const float*)d_in[3];
  const float* W1 = (const float*)d_in[4];
  const float* b1 = (const float*)d_in[5];
  const float* W2 = (const float*)d_in[6];
  const float* b2 = (const float*)d_in[7];

  // ws footprint: 2*16384*128 + 2*128*256 shorts = 8.1 MB
  short* ws  = (short*)d_ws;
  short* q1p = ws;                                   // 16384*128 f16
  short* q2p = q1p + (size_t)16384 * 128;
  short* wt1 = q2p + (size_t)16384 * 128;            // 128*256 f16
  short* wt2 = wt1 + (size_t)128 * 256;
  float* out = (float*)d_out;

  transW_k<<<dim3(2), dim3(256), 0, stream>>>(W1, W2, wt1, wt2);
  proj_k<<<dim3(256), dim3(256), 0, stream>>>(k1, wt1, b1, q1p);
  proj_k<<<dim3(256), dim3(256), 0, stream>>>(k2, wt2, b2, q2p);
  attn_k<<<dim3(32, 8, 2), dim3(256), 0, stream>>>(q1p, q2p, v1, v2, out);
}

// Round 8
// 289.896 us; speedup vs baseline: 1.1022x; 1.1022x over previous
//
#include <hip/hip_runtime.h>
#include <hip/hip_bf16.h>

#define B_  8
#define N_  2048
#define KD_ 256
#define AD_ 128
#define VD_ 256

using s16x8 = __attribute__((ext_vector_type(8))) short;
using f16x8 = __attribute__((ext_vector_type(8))) _Float16;
using h2    = __attribute__((ext_vector_type(2))) __fp16;
using f32x4 = __attribute__((ext_vector_type(4))) float;

__device__ __forceinline__ f32x4 mfma16(s16x8 a, s16x8 b, f32x4 c) {
  return __builtin_amdgcn_mfma_f32_16x16x32_f16(
      __builtin_bit_cast(f16x8, a), __builtin_bit_cast(f16x8, b), c, 0, 0, 0);
}
__device__ __forceinline__ short f2h(float f) {
  _Float16 h = (_Float16)f;
  return *reinterpret_cast<short*>(&h);
}
// 8 consecutive fp32 -> f16x8 via packed cvt
__device__ __forceinline__ s16x8 cvt8(const float* __restrict__ p) {
  union { s16x8 v; h2 h[4]; } u;
  f32x4 a = *(const f32x4*)p;
  f32x4 bq = *(const f32x4*)(p + 4);
  u.h[0] = __builtin_amdgcn_cvt_pkrtz(a[0], a[1]);
  u.h[1] = __builtin_amdgcn_cvt_pkrtz(a[2], a[3]);
  u.h[2] = __builtin_amdgcn_cvt_pkrtz(bq[0], bq[1]);
  u.h[3] = __builtin_amdgcn_cvt_pkrtz(bq[2], bq[3]);
  return u.v;
}

// ---------------- W transpose+convert: WT[n][k] = f16(W[k][n]) --------------
__global__ void transW_k(const float* __restrict__ W1, const float* __restrict__ W2,
                         short* __restrict__ WT1, short* __restrict__ WT2) {
  const float* W = blockIdx.x ? W2 : W1;
  short* WT      = blockIdx.x ? WT2 : WT1;
  for (int i = threadIdx.x; i < KD_ * AD_; i += blockDim.x) {
    int k = i >> 7, n = i & 127;
    WT[n * KD_ + k] = f2h(W[i]);
  }
}

// ---------------- V transpose+convert, tile-major ---------------------------
// vt[b][kt][vr][64keys] f16; reads coalesced fp32 rows, writes b128/thread-row.
__global__ __launch_bounds__(256) void transV_k(
    const float* __restrict__ v1, const float* __restrict__ v2,
    short* __restrict__ vt1, short* __restrict__ vt2) {
  const int t  = threadIdx.x;           // = vr (0..255)
  const int kt = blockIdx.x;
  const int b  = blockIdx.y;
  const float* src = blockIdx.z ? v2 : v1;
  short*       dst = blockIdx.z ? vt2 : vt1;
  const size_t base = ((size_t)(b * 32 + kt)) * (256 * 64);
  #pragma unroll
  for (int i = 0; i < 8; i++) {         // key-chunk of 8
    float x[8];
    #pragma unroll
    for (int kk = 0; kk < 8; kk++)
      x[kk] = src[((size_t)(b * N_ + kt * 64 + i * 8 + kk)) * VD_ + t];
    union { s16x8 v; h2 h[4]; } u;
    #pragma unroll
    for (int kk = 0; kk < 4; kk++)
      u.h[kk] = __builtin_amdgcn_cvt_pkrtz(x[2 * kk], x[2 * kk + 1]);
    *(s16x8*)&dst[base + (size_t)t * 64 + i * 8] = u.v;
  }
}

// ---------------- projection: Y[m][n] = f16(X@W + bias) ---------------------
__global__ __launch_bounds__(256, 2) void proj_k(
    const float* __restrict__ X, const short* __restrict__ WT,
    const float* __restrict__ bias, short* __restrict__ Y) {
  __shared__ __align__(16) short sA[64 * 264];
  const int t    = threadIdx.x;
  const int m0   = blockIdx.x * 64;
  const int lane = t & 63, wave = t >> 6, quad = lane >> 4, l16 = lane & 15;
  #pragma unroll
  for (int i = 0; i < 8; i++) {
    int chunk = i * 256 + t, row = chunk >> 5, c8 = chunk & 31;
    *(s16x8*)&sA[row * 264 + c8 * 8] =
        cvt8(&X[((size_t)(m0 + row)) * KD_ + c8 * 8]);
  }
  __syncthreads();
  f32x4 acc[8];
  #pragma unroll
  for (int nt = 0; nt < 8; nt++) acc[nt] = (f32x4){0.f, 0.f, 0.f, 0.f};
  #pragma unroll
  for (int ks = 0; ks < 8; ks++) {
    s16x8 a = *(const s16x8*)&sA[(wave * 16 + l16) * 264 + ks * 32 + quad * 8];
    #pragma unroll
    for (int nt = 0; nt < 8; nt++) {
      s16x8 bf = *(const s16x8*)&WT[(nt * 16 + l16) * KD_ + ks * 32 + quad * 8];
      acc[nt] = mfma16(a, bf, acc[nt]);
    }
  }
  #pragma unroll
  for (int nt = 0; nt < 8; nt++) {
    float bv = bias[nt * 16 + l16];
    #pragma unroll
    for (int r = 0; r < 4; r++) {
      int row = m0 + wave * 16 + quad * 4 + r;
      Y[(size_t)row * AD_ + nt * 16 + l16] = f2h(acc[nt][r] + bv);
    }
  }
}

// ---------------- flash attention with prefetch -----------------------------
// Q,K: [B][N][128] f16; Vt: tile-major f16 [b][kt][vr][64]
__global__ __launch_bounds__(256, 2) void attn_k(
    const short* __restrict__ q1p, const short* __restrict__ q2p,
    const short* __restrict__ vt1, const short* __restrict__ vt2,
    float* __restrict__ out) {
  __shared__ __align__(16) short sK[64 * 136];     // 17408 B
  __shared__ __align__(16) short sVT[256 * 64];    // 32768 B, XOR-swizzled
  __shared__ __align__(16) short sP[4][16 * 64];   // 8192 B,  XOR-swizzled

  const int t    = threadIdx.x;
  const int lane = t & 63, wave = t >> 6, quad = lane >> 4, l16 = lane & 15;
  const int q0   = blockIdx.x * 64;
  const int b    = blockIdx.y;
  const int pass = blockIdx.z;
  const short* Q  = pass ? q2p : q1p;
  const short* K  = pass ? q1p : q2p;
  const short* Vt = pass ? vt1 : vt2;
  float* O = out + (size_t)pass * ((size_t)B_ * N_ * VD_);
  const size_t vbase0 = (size_t)b * 32 * (256 * 64);

  // stage Q tile into sK, pull fragments to regs
  #pragma unroll
  for (int i = 0; i < 4; i++) {
    int chunk = i * 256 + t, row = chunk >> 4, c8 = chunk & 15;
    *(s16x8*)&sK[row * 136 + c8 * 8] =
        *(const s16x8*)&Q[((size_t)(b * N_ + q0 + row)) * AD_ + c8 * 8];
  }
  __syncthreads();
  s16x8 qf[4];
  #pragma unroll
  for (int ks = 0; ks < 4; ks++)
    qf[ks] = *(const s16x8*)&sK[(wave * 16 + l16) * 136 + ks * 32 + quad * 8];
  __syncthreads();

  float m_i[4], l_i[4];
  #pragma unroll
  for (int r = 0; r < 4; r++) { m_i[r] = -1e30f; l_i[r] = 0.f; }
  f32x4 acc[16];
  #pragma unroll
  for (int c = 0; c < 16; c++) acc[c] = (f32x4){0.f, 0.f, 0.f, 0.f};

  s16x8 pk[4], pv[8];
  auto loadKV = [&](int kt) {
    const size_t krow = (size_t)(b * N_ + kt * 64);
    #pragma unroll
    for (int i = 0; i < 4; i++) {
      int chunk = i * 256 + t, row = chunk >> 4, c8 = chunk & 15;
      pk[i] = *(const s16x8*)&K[(krow + row) * AD_ + c8 * 8];
    }
    const size_t vb = vbase0 + (size_t)kt * (256 * 64);
    #pragma unroll
    for (int i = 0; i < 8; i++)
      pv[i] = *(const s16x8*)&Vt[vb + (size_t)(i * 256 + t) * 8];
  };
  auto storeKV = [&]() {
    #pragma unroll
    for (int i = 0; i < 4; i++) {
      int chunk = i * 256 + t, row = chunk >> 4, c8 = chunk & 15;
      *(s16x8*)&sK[row * 136 + c8 * 8] = pk[i];
    }
    #pragma unroll
    for (int i = 0; i < 8; i++) {
      int idx = i * 256 + t, vr = idx >> 3, c = idx & 7;
      *(s16x8*)&sVT[vr * 64 + ((c ^ (vr & 7)) * 8)] = pv[i];
    }
  };

  loadKV(0);
  storeKV();
  __syncthreads();

  for (int kt = 0; kt < 32; kt++) {
    if (kt + 1 < 32) loadKV(kt + 1);   // prefetch into regs, no wait yet

    // S = Q K^T
    f32x4 s[4];
    #pragma unroll
    for (int nt = 0; nt < 4; nt++) s[nt] = (f32x4){0.f, 0.f, 0.f, 0.f};
    #pragma unroll
    for (int ks = 0; ks < 4; ks++) {
      #pragma unroll
      for (int nt = 0; nt < 4; nt++) {
        s16x8 bfrag = *(const s16x8*)&sK[(nt * 16 + l16) * 136 + ks * 32 + quad * 8];
        s[nt] = mfma16(qf[ks], bfrag, s[nt]);
      }
    }

    // online softmax
    float alpha[4];
    #pragma unroll
    for (int r = 0; r < 4; r++) {
      float m = fmaxf(fmaxf(s[0][r], s[1][r]), fmaxf(s[2][r], s[3][r]));
      #pragma unroll
      for (int off = 1; off < 16; off <<= 1) m = fmaxf(m, __shfl_xor(m, off));
      float mn = fmaxf(m_i[r], m);
      alpha[r] = __expf(m_i[r] - mn);
      m_i[r]   = mn;
      float sum = 0.f;
      #pragma unroll
      for (int nt = 0; nt < 4; nt++) {
        float p = __expf(s[nt][r] - mn);
        s[nt][r] = p;
        sum += p;
      }
      #pragma unroll
      for (int off = 1; off < 16; off <<= 1) sum += __shfl_xor(sum, off);
      l_i[r] = l_i[r] * alpha[r] + sum;
    }
    #pragma unroll
    for (int c = 0; c < 16; c++) {
      #pragma unroll
      for (int r = 0; r < 4; r++) acc[c][r] *= alpha[r];
    }

    // P: D-layout -> per-wave swizzled LDS (row, colchunk^row&7)
    #pragma unroll
    for (int nt = 0; nt < 4; nt++) {
      int ch = 2 * nt + (l16 >> 3);
      #pragma unroll
      for (int r = 0; r < 4; r++) {
        int row = quad * 4 + r;
        sP[wave][row * 64 + ((ch ^ (row & 7)) * 8) + (l16 & 7)] = f2h(s[nt][r]);
      }
    }

    // O += P @ V  (same-wave sP write->read, ordered by lgkmcnt)
    #pragma unroll
    for (int ks2 = 0; ks2 < 2; ks2++) {
      int cx = ((ks2 * 4 + quad) ^ (l16 & 7)) * 8;
      s16x8 af = *(const s16x8*)&sP[wave][l16 * 64 + cx];
      #pragma unroll
      for (int nt2 = 0; nt2 < 16; nt2++) {
        s16x8 bf = *(const s16x8*)&sVT[(nt2 * 16 + l16) * 64 + cx];
        acc[nt2] = mfma16(af, bf, acc[nt2]);
      }
    }
    __syncthreads();                    // all waves done with sK/sVT
    if (kt + 1 < 32) {
      storeKV();                        // commit prefetched tile
      __syncthreads();
    }
  }

  // epilogue
  #pragma unroll
  for (int r = 0; r < 4; r++) {
    float inv = 1.f / l_i[r];
    int row = q0 + wave * 16 + quad * 4 + r;
    #pragma unroll
    for (int nt2 = 0; nt2 < 16; nt2++)
      O[((size_t)(b * N_ + row)) * VD_ + nt2 * 16 + l16] = acc[nt2][r] * inv;
  }
}

extern "C" void kernel_launch(void* const* d_in, const int* in_sizes, int n_in,
                              void* d_out, int out_size, void* d_ws, size_t ws_size,
                              hipStream_t stream) {
  const float* k1 = (const float*)d_in[0];
  const float* k2 = (const float*)d_in[1];
  const float* v1 = (const float*)d_in[2];
  const float* v2 = (const float*)d_in[3];
  const float* W1 = (const float*)d_in[4];
  const float* b1 = (const float*)d_in[5];
  const float* W2 = (const float*)d_in[6];
  const float* b2 = (const float*)d_in[7];

  short* ws  = (short*)d_ws;
  short* q1p = ws;                                   // 16384*128 f16 (4 MB)
  short* q2p = q1p + (size_t)16384 * 128;
  short* wt1 = q2p + (size_t)16384 * 128;            // 128*256 f16
  short* wt2 = wt1 + (size_t)128 * 256;
  short* vt1 = wt2 + (size_t)128 * 256;              // 8*32*256*64 f16 (8.4 MB)
  short* vt2 = vt1 + (size_t)B_ * 32 * 256 * 64;
  float* out = (float*)d_out;

  transW_k<<<dim3(2), dim3(256), 0, stream>>>(W1, W2, wt1, wt2);
  transV_k<<<dim3(32, 8, 2), dim3(256), 0, stream>>>(v1, v2, vt1, vt2);
  proj_k<<<dim3(256), dim3(256), 0, stream>>>(k1, wt1, b1, q1p);
  proj_k<<<dim3(256), dim3(256), 0, stream>>>(k2, wt2, b2, q2p);
  attn_k<<<dim3(32, 8, 2), dim3(256), 0, stream>>>(q1p, q2p, vt1, vt2, out);
}